// Round 22
// baseline (196.673 us; speedup 1.0000x reference)
//
#include <hip/hip_runtime.h>
#include <hip/hip_bf16.h>
#include <math.h>
#include <type_traits>

typedef __bf16 bf16_t;
typedef __bf16 bf16x8 __attribute__((ext_vector_type(8)));
typedef float f32x4 __attribute__((ext_vector_type(4)));

__device__ __forceinline__ void gload_lds16(const void* g, void* l) {
  __builtin_amdgcn_global_load_lds((const __attribute__((address_space(1))) void*)g,
                                   (__attribute__((address_space(3))) void*)l, 16, 0, 0);
}

// ------------- transpose + cast: in fp32 [K][N] -> out bf16 [N][K] -------------
__global__ void transk(const float* __restrict__ in, bf16_t* __restrict__ out,
                       int K, int N) {
  __shared__ float t[32][33];
  int n0 = blockIdx.x * 32, k0 = blockIdx.y * 32;
  int tx = threadIdx.x & 31, ty = threadIdx.x >> 5;  // ty 0..7
#pragma unroll
  for (int r = ty; r < 32; r += 8) t[r][tx] = in[(size_t)(k0 + r) * N + n0 + tx];
  __syncthreads();
#pragma unroll
  for (int r = ty; r < 32; r += 8)
    out[(size_t)(n0 + r) * K + k0 + tx] = (bf16_t)t[tx][r];
}

// ------------- row offsets: ro[n] = lower_bound(dst, n) (dst sorted) -------------
__global__ void rowoffk(const int* __restrict__ dst, int* __restrict__ ro, int N, int E) {
  int n = blockIdx.x * blockDim.x + threadIdx.x;
  if (n > N) return;
  if (n == N) { ro[N] = E; return; }
  int lo = 0, hi = E;
  while (lo < hi) { int mid = (lo + hi) >> 1; if (dst[mid] < n) lo = mid + 1; else hi = mid; }
  ro[n] = lo;
}

// ------------- edge weights (edge-parallel, streaming), per-head PLANES -------
__global__ void edgek(const float* __restrict__ el, const float* __restrict__ er,
                      const int* __restrict__ src, const int* __restrict__ dst,
                      float* __restrict__ pw, int E) {
  int e = blockIdx.x * blockDim.x + threadIdx.x;
  if (e >= E) return;
  int s = src[e], d = dst[e];
  float4 ev = *(const float4*)(el + (size_t)s * 4);
  float4 rv = *(const float4*)(er + (size_t)d * 4);
  float c;
  c = ev.x + rv.x; c = c >= 0.f ? c : 0.2f * c; pw[e] = __expf(c);
  c = ev.y + rv.y; c = c >= 0.f ? c : 0.2f * c; pw[(size_t)E + e] = __expf(c);
  c = ev.z + rv.z; c = c >= 0.f ? c : 0.2f * c; pw[(size_t)2 * E + e] = __expf(c);
  c = ev.w + rv.w; c = c >= 0.f ? c : 0.2f * c; pw[(size_t)3 * E + e] = __expf(c);
}

// ------------- gather-aggregate, DIM-SLICE x XCD partitioned, batch-8 ----------
// slice = blockIdx.x & 7 -> round-robin XCD mapping pins each 64-dim slice of
// Hb (2.56 MB) into one XCD's 4 MB L2 (verified: FETCH 140->24 MB in r6).
// Batch-8 is the measured optimum (r5 batch-4 and r17 batch-16 both slower).
#define GK_NPB 32  // nodes per block (4 waves x 8 groups); 20000 = 625*32
__global__ __launch_bounds__(256) void gatherk(
    const bf16_t* __restrict__ Hb, const float* __restrict__ pw,
    const int* __restrict__ src, const int* __restrict__ ro,
    const float* __restrict__ bias, bf16_t* __restrict__ out, int N, int E) {
  const int slice = blockIdx.x & 7;
  const int group = blockIdx.x >> 3;
  const int w = threadIdx.x >> 6, lane = threadIdx.x & 63;
  const int g = lane >> 3;               // node sub-index within wave
  const int oct = lane & 7;              // dim octet within slice
  const int head = slice >> 1;
  const float* __restrict__ ph = pw + (size_t)head * E;
  const int dimbase = slice * 64 + oct * 8;

  const int n = group * GK_NPB + w * 8 + g;
  const int e0 = ro[n], e1 = ro[n + 1];

  float acc[8] = {0.f, 0.f, 0.f, 0.f, 0.f, 0.f, 0.f, 0.f};
  float psum = 0.f;

  for (int eb = e0 & ~7; eb < e1; eb += 8) {
    const int4 sv0 = *(const int4*)(src + eb);
    const int4 sv1 = *(const int4*)(src + eb + 4);
    const float4 pv0 = *(const float4*)(ph + eb);
    const float4 pv1 = *(const float4*)(ph + eb + 4);
    int ss[8]; float pp[8];
    ss[0] = sv0.x; ss[1] = sv0.y; ss[2] = sv0.z; ss[3] = sv0.w;
    ss[4] = sv1.x; ss[5] = sv1.y; ss[6] = sv1.z; ss[7] = sv1.w;
    pp[0] = pv0.x; pp[1] = pv0.y; pp[2] = pv0.z; pp[3] = pv0.w;
    pp[4] = pv1.x; pp[5] = pv1.y; pp[6] = pv1.z; pp[7] = pv1.w;
#pragma unroll
    for (int j = 0; j < 8; j++) {
      const int e = eb + j;
      if (e < e0 || e >= e1) pp[j] = 0.f;
    }
    bf16x8 v[8];
#pragma unroll
    for (int j = 0; j < 8; j++)
      v[j] = *(const bf16x8*)(Hb + (size_t)ss[j] * 512 + dimbase);
#pragma unroll
    for (int j = 0; j < 8; j++) {
      psum += pp[j];
#pragma unroll
      for (int t = 0; t < 8; t++) acc[t] += pp[j] * (float)v[j][t];
    }
  }

  const float ih = psum > 0.f ? 1.0f / psum : 0.f;
  const float4 b0 = *(const float4*)(bias + dimbase);
  const float4 b1 = *(const float4*)(bias + dimbase + 4);
  bf16x8 o; float vv;
  vv = acc[0] * ih + b0.x; o[0] = (bf16_t)(vv > 0.f ? vv : expm1f(vv));
  vv = acc[1] * ih + b0.y; o[1] = (bf16_t)(vv > 0.f ? vv : expm1f(vv));
  vv = acc[2] * ih + b0.z; o[2] = (bf16_t)(vv > 0.f ? vv : expm1f(vv));
  vv = acc[3] * ih + b0.w; o[3] = (bf16_t)(vv > 0.f ? vv : expm1f(vv));
  vv = acc[4] * ih + b1.x; o[4] = (bf16_t)(vv > 0.f ? vv : expm1f(vv));
  vv = acc[5] * ih + b1.y; o[5] = (bf16_t)(vv > 0.f ? vv : expm1f(vv));
  vv = acc[6] * ih + b1.z; o[6] = (bf16_t)(vv > 0.f ? vv : expm1f(vv));
  vv = acc[7] * ih + b1.w; o[7] = (bf16_t)(vv > 0.f ? vv : expm1f(vv));
  *(bf16x8*)(out + (size_t)n * 512 + dimbase) = o;
}

// ------------- bf16 MFMA GEMM, BK=64, single-buffered 2-barrier -------------
// r22: BM=64 for the two 512-wide GEMMs. UNLIKE r10's BN=64 regression (which
// halved per-barrier MFMA), BM=64/BN=128 keeps per-wave MFMA/barrier constant
// (wave tile 64x64 -> 32x64, both 8 MFMA/kk) while DOUBLING resident blocks
// (grid 628->1252, 2.45->~4.2/CU; LDS 50->33 KB fits 4/CU) -> m114 inter-block
// overlap hides the per-step vmcnt(0) drain. seg-XOR swizzle as before.
// AF32=1: A fp32 (GEMM1, fused cast). EPI=0: bf16 C. EPI=1: fp32 elu(C+bias).
// EPI=2: bf16 C + fused el/er (BN=128==D: block == one head; writer-select
// with compile-time indices, guard L < MF*4).
template <int BM, int BN, int WM, int WN, int EPI, int AF32>
__global__ __launch_bounds__(256) void gemm_bt(
    const void* __restrict__ A, const bf16_t* __restrict__ Bt,
    void* __restrict__ C, const float* __restrict__ bias,
    const float* __restrict__ al, const float* __restrict__ ar,
    float* __restrict__ el, float* __restrict__ er,
    int M, int N, int K) {
  constexpr int BK = 64;
  constexpr int WTM = BM / WM, WTN = BN / WN;
  constexpr int MF = WTM / 16, NF = WTN / 16;
  using AT = typename std::conditional<AF32, float, bf16_t>::type;

  __shared__ AT sA[BM][BK];
  __shared__ bf16_t sB[BN][BK];
  __shared__ float s_red[2][BM][2];   // [el/er][row][wc] (EPI==2 only)

  const bf16_t* __restrict__ Ab = (const bf16_t*)A;
  const float* __restrict__ Af = (const float*)A;

  const int tid = threadIdx.x;
  const int wid = tid >> 6, lane = tid & 63;
  const int wr = wid / WN, wc = wid % WN;

  // XCD-chunked bijective swizzle (m204)
  const int nby = N / BN;
  const int nwg = gridDim.x;
  const int q = nwg >> 3, r = nwg & 7;
  const int xcd = blockIdx.x & 7, pos = blockIdx.x >> 3;
  const int wg = (xcd < r ? xcd * (q + 1) : r * (q + 1) + (xcd - r) * q) + pos;
  const int row0 = (wg / nby) * BM;
  const int col0 = (wg % nby) * BN;

  f32x4 acc[MF][NF];
#pragma unroll
  for (int i = 0; i < MF; i++)
#pragma unroll
    for (int j = 0; j < NF; j++) acc[i][j] = (f32x4){0.f, 0.f, 0.f, 0.f};

  // bf16 staging: 1 KB/issue = 8 rows of 128 B; lane -> row l>>3, phys seg l&7
  const int b_r = lane >> 3, b_p = lane & 7;
  // fp32 staging: 1 KB/issue = 4 rows of 256 B; lane -> row l>>4, phys seg l&15
  const int a_r = lane >> 4, a_p = lane & 15;

  for (int k0 = 0; k0 < K; k0 += BK) {
    if constexpr (AF32) {
#pragma unroll
      for (int j = 0; j < BM / 16; j++) {      // 4 rows per issue
        const int rj = (j * 4 + wid) * 4;
        const int row = rj + a_r;
        int grow = row0 + row; if (grow > M - 1) grow = M - 1;
        const int s = a_p ^ (row & 7);         // inverse swizzle on source
        gload_lds16(Af + (size_t)grow * K + k0 + s * 4, &sA[rj][0]);
      }
    } else {
#pragma unroll
      for (int j = 0; j < BM / 32; j++) {      // 8 rows per issue
        const int rj = (j * 4 + wid) * 8;
        const int row = rj + b_r;
        int grow = row0 + row; if (grow > M - 1) grow = M - 1;
        const int s = b_p ^ (row & 7);
        gload_lds16(Ab + (size_t)grow * K + k0 + s * 8, &sA[rj][0]);
      }
    }
#pragma unroll
    for (int j = 0; j < BN / 32; j++) {
      const int rj = (j * 4 + wid) * 8;
      const int row = rj + b_r;
      const int s = b_p ^ (row & 7);
      gload_lds16(Bt + (size_t)(col0 + row) * K + k0 + s * 8, &sB[rj][0]);
    }
    __syncthreads();

#pragma unroll
    for (int kk = 0; kk < BK; kk += 32) {
      bf16x8 af[MF], bfr[NF];
#pragma unroll
      for (int i = 0; i < MF; i++) {
        const int row = wr * WTM + i * 16 + (lane & 15);
        if constexpr (AF32) {
          const int s0 = kk / 4 + (lane >> 4) * 2;      // 16B segs of 4 floats
          const int p0 = s0 ^ (row & 7), p1 = (s0 + 1) ^ (row & 7);
          const f32x4 a0 = *(const f32x4*)&((const float*)&sA[row][0])[p0 * 4];
          const f32x4 a1 = *(const f32x4*)&((const float*)&sA[row][0])[p1 * 4];
#pragma unroll
          for (int t = 0; t < 4; t++) {
            af[i][t] = (bf16_t)a0[t];
            af[i][t + 4] = (bf16_t)a1[t];
          }
        } else {
          const int s = kk / 8 + (lane >> 4);           // 16B segs of 8 bf16
          const int p = s ^ (row & 7);
          af[i] = *(const bf16x8*)&((const bf16_t*)&sA[row][0])[p * 8];
        }
      }
#pragma unroll
      for (int j = 0; j < NF; j++) {
        const int row = wc * WTN + j * 16 + (lane & 15);
        const int s = kk / 8 + (lane >> 4);
        const int p = s ^ (row & 7);
        bfr[j] = *(const bf16x8*)&((const bf16_t*)&sB[row][0])[p * 8];
      }
#pragma unroll
      for (int i = 0; i < MF; i++)
#pragma unroll
        for (int j = 0; j < NF; j++)
          acc[i][j] = __builtin_amdgcn_mfma_f32_16x16x32_bf16(af[i], bfr[j], acc[i][j], 0, 0, 0);
    }
    __syncthreads();
  }

  // ---- C store ----
#pragma unroll
  for (int i = 0; i < MF; i++) {
#pragma unroll
    for (int j = 0; j < NF; j++) {
#pragma unroll
      for (int rr = 0; rr < 4; rr++) {
        int row = row0 + wr * WTM + i * 16 + (lane >> 4) * 4 + rr;
        int col = col0 + wc * WTN + j * 16 + (lane & 15);
        if (row < M) {
          float v = acc[i][j][rr];
          if constexpr (EPI == 1) {
            v += bias[col];
            v = v > 0.f ? v : expm1f(v);
            ((float*)C)[(size_t)row * N + col] = v;
          } else {
            ((bf16_t*)C)[(size_t)row * N + col] = (bf16_t)v;
          }
        }
      }
    }
  }

  // ---- fused el/er (EPI==2): this block's col range == head h ----
  if constexpr (EPI == 2) {
    const int h = col0 >> 7;  // BN==128==D
    float alv[NF], arv[NF];
#pragma unroll
    for (int j = 0; j < NF; j++) {
      const int d = wc * WTN + j * 16 + (lane & 15);   // col within head
      alv[j] = al[h * 128 + d];
      arv[j] = ar[h * 128 + d];
    }
    float tl[MF][4], tr[MF][4];
#pragma unroll
    for (int i = 0; i < MF; i++)
#pragma unroll
      for (int rr = 0; rr < 4; rr++) {
        float sl = 0.f, sr2 = 0.f;
#pragma unroll
        for (int j = 0; j < NF; j++) {
          sl  += acc[i][j][rr] * alv[j];
          sr2 += acc[i][j][rr] * arv[j];
        }
        tl[i][rr] = sl; tr[i][rr] = sr2;
      }
    // reduce across the 16-lane col-group (rows depend only on lane>>4)
#pragma unroll
    for (int msk = 1; msk < 16; msk <<= 1)
#pragma unroll
      for (int i = 0; i < MF; i++)
#pragma unroll
        for (int rr = 0; rr < 4; rr++) {
          tl[i][rr] += __shfl_xor(tl[i][rr], msk);
          tr[i][rr] += __shfl_xor(tr[i][rr], msk);
        }
    // writer select: compile-time indices only (rule #20)
    float outl = 0.f, outr = 0.f;
#pragma unroll
    for (int i = 0; i < MF; i++)
#pragma unroll
      for (int rr = 0; rr < 4; rr++)
        if ((lane & 15) == i * 4 + rr) { outl = tl[i][rr]; outr = tr[i][rr]; }
    {
      const int L = lane & 15;
      if (L < MF * 4) {
        const int rloc = wr * WTM + (L >> 2) * 16 + (lane >> 4) * 4 + (L & 3);
        s_red[0][rloc][wc] = outl;
        s_red[1][rloc][wc] = outr;
      }
    }
    __syncthreads();
    if (tid < BM) {
      const int row = row0 + tid;
      if (row < M) {
        el[(size_t)row * 4 + h] = s_red[0][tid][0] + s_red[0][tid][1];
        er[(size_t)row * 4 + h] = s_red[1][tid][0] + s_red[1][tid][1];
      }
    }
  }
}

extern "C" void kernel_launch(void* const* d_in, const int* in_sizes, int n_in,
                              void* d_out, int out_size, void* d_ws, size_t ws_size,
                              hipStream_t stream) {
  const float* feature = (const float*)d_in[0];
  const int* src = (const int*)d_in[1];
  const int* dst = (const int*)d_in[2];
  const float* W1 = (const float*)d_in[3];
  const float* al1 = (const float*)d_in[4];
  const float* ar1 = (const float*)d_in[5];
  const float* b1 = (const float*)d_in[6];
  const float* W2 = (const float*)d_in[7];
  const float* al2 = (const float*)d_in[8];
  const float* ar2 = (const float*)d_in[9];
  const float* b2 = (const float*)d_in[10];
  const float* Wfc = (const float*)d_in[11];
  const float* bfc = (const float*)d_in[12];

  const int N = 20000, E = 320000, INF = 1280, HD = 512;

  char* ws = (char*)d_ws;
  size_t off = 0;
  auto alloc = [&](size_t bytes) {
    void* p = ws + off;
    off += (bytes + 255) & ~(size_t)255;
    return p;
  };
  bf16_t* W1t = (bf16_t*)alloc((size_t)HD * INF * 2);
  bf16_t* W2t = (bf16_t*)alloc((size_t)HD * HD * 2);
  bf16_t* Wft = (bf16_t*)alloc((size_t)64 * HD * 2);
  bf16_t* Hb  = (bf16_t*)alloc((size_t)N * HD * 2);    // 20.5 MB
  bf16_t* Xn  = (bf16_t*)alloc((size_t)N * HD * 2);    // 20.5 MB
  float* el = (float*)alloc((size_t)N * 4 * 4);
  float* er = (float*)alloc((size_t)N * 4 * 4);
  float* pw = (float*)alloc((size_t)E * 4 * 4);        // 5.1 MB, planes [4][E]
  int* ro = (int*)alloc((size_t)(N + 1) * 4);

  // preprocessing
  {
    dim3 g(HD / 32, INF / 32);
    transk<<<g, 256, 0, stream>>>(W1, W1t, INF, HD);
  }
  {
    dim3 g(HD / 32, HD / 32);
    transk<<<g, 256, 0, stream>>>(W2, W2t, HD, HD);
  }
  {
    dim3 g(64 / 32, HD / 32);
    transk<<<g, 256, 0, stream>>>(Wfc, Wft, HD, 64);
  }
  rowoffk<<<(N + 1 + 255) / 256, 256, 0, stream>>>(dst, ro, N, E);

  const int nbx64 = (N + 63) / 64;        // 313
  const int nbx = (N + 127) / 128;        // 157
  const int gatherBlocks = (N / GK_NPB) * 8;   // 625 groups x 8 slices
  const int edgeBlocks = (E + 255) / 256;

  // layer 1: A = fp32 feature (cast fused), BM=64 (grid 1252), fused el/er
  gemm_bt<64, 128, 2, 2, 2, 1><<<nbx64 * (HD / 128), 256, 0, stream>>>(
      feature, W1t, Hb, nullptr, al1, ar1, el, er, N, HD, INF);
  edgek<<<edgeBlocks, 256, 0, stream>>>(el, er, src, dst, pw, E);
  gatherk<<<gatherBlocks, 256, 0, stream>>>(Hb, pw, src, ro, b1, Xn, N, E);

  // layer 2: bf16 path, BM=64, fused el/er
  gemm_bt<64, 128, 2, 2, 2, 0><<<nbx64 * (HD / 128), 256, 0, stream>>>(
      Xn, W2t, Hb, nullptr, al2, ar2, el, er, N, HD, HD);
  edgek<<<edgeBlocks, 256, 0, stream>>>(el, er, src, dst, pw, E);
  gatherk<<<gatherBlocks, 256, 0, stream>>>(Hb, pw, src, ro, b2, Xn, N, E);

  // final FC + elu -> d_out (fp32)
  gemm_bt<128, 64, 4, 1, 1, 0><<<nbx, 256, 0, stream>>>(
      Xn, Wft, d_out, bfc, nullptr, nullptr, nullptr, nullptr, N, 64, HD);
}

// Round 23
// 193.332 us; speedup vs baseline: 1.0173x; 1.0173x over previous
//
#include <hip/hip_runtime.h>
#include <hip/hip_bf16.h>
#include <math.h>
#include <type_traits>

typedef __bf16 bf16_t;
typedef __bf16 bf16x8 __attribute__((ext_vector_type(8)));
typedef float f32x4 __attribute__((ext_vector_type(4)));

__device__ __forceinline__ void gload_lds16(const void* g, void* l) {
  __builtin_amdgcn_global_load_lds((const __attribute__((address_space(1))) void*)g,
                                   (__attribute__((address_space(3))) void*)l, 16, 0, 0);
}

// ------------- transpose + cast: in fp32 [K][N] -> out bf16 [N][K] -------------
__global__ void transk(const float* __restrict__ in, bf16_t* __restrict__ out,
                       int K, int N) {
  __shared__ float t[32][33];
  int n0 = blockIdx.x * 32, k0 = blockIdx.y * 32;
  int tx = threadIdx.x & 31, ty = threadIdx.x >> 5;  // ty 0..7
#pragma unroll
  for (int r = ty; r < 32; r += 8) t[r][tx] = in[(size_t)(k0 + r) * N + n0 + tx];
  __syncthreads();
#pragma unroll
  for (int r = ty; r < 32; r += 8)
    out[(size_t)(n0 + r) * K + k0 + tx] = (bf16_t)t[tx][r];
}

// ------------- row offsets: ro[n] = lower_bound(dst, n) (dst sorted) -------------
__global__ void rowoffk(const int* __restrict__ dst, int* __restrict__ ro, int N, int E) {
  int n = blockIdx.x * blockDim.x + threadIdx.x;
  if (n > N) return;
  if (n == N) { ro[N] = E; return; }
  int lo = 0, hi = E;
  while (lo < hi) { int mid = (lo + hi) >> 1; if (dst[mid] < n) lo = mid + 1; else hi = mid; }
  ro[n] = lo;
}

// ------------- edge weights (edge-parallel, streaming), per-head PLANES -------
__global__ void edgek(const float* __restrict__ el, const float* __restrict__ er,
                      const int* __restrict__ src, const int* __restrict__ dst,
                      float* __restrict__ pw, int E) {
  int e = blockIdx.x * blockDim.x + threadIdx.x;
  if (e >= E) return;
  int s = src[e], d = dst[e];
  float4 ev = *(const float4*)(el + (size_t)s * 4);
  float4 rv = *(const float4*)(er + (size_t)d * 4);
  float c;
  c = ev.x + rv.x; c = c >= 0.f ? c : 0.2f * c; pw[e] = __expf(c);
  c = ev.y + rv.y; c = c >= 0.f ? c : 0.2f * c; pw[(size_t)E + e] = __expf(c);
  c = ev.z + rv.z; c = c >= 0.f ? c : 0.2f * c; pw[(size_t)2 * E + e] = __expf(c);
  c = ev.w + rv.w; c = c >= 0.f ? c : 0.2f * c; pw[(size_t)3 * E + e] = __expf(c);
}

// ------------- gather-aggregate, DIM-SLICE x XCD partitioned, batch-8 ----------
// slice = blockIdx.x & 7 -> round-robin XCD mapping pins each 64-dim slice of
// Hb (2.56 MB) into one XCD's 4 MB L2 (verified: FETCH 140->24 MB in r6).
// Batch-8 is the measured optimum (r5 batch-4 and r17 batch-16 both slower).
#define GK_NPB 32  // nodes per block (4 waves x 8 groups); 20000 = 625*32
__global__ __launch_bounds__(256) void gatherk(
    const bf16_t* __restrict__ Hb, const float* __restrict__ pw,
    const int* __restrict__ src, const int* __restrict__ ro,
    const float* __restrict__ bias, bf16_t* __restrict__ out, int N, int E) {
  const int slice = blockIdx.x & 7;
  const int group = blockIdx.x >> 3;
  const int w = threadIdx.x >> 6, lane = threadIdx.x & 63;
  const int g = lane >> 3;               // node sub-index within wave
  const int oct = lane & 7;              // dim octet within slice
  const int head = slice >> 1;
  const float* __restrict__ ph = pw + (size_t)head * E;
  const int dimbase = slice * 64 + oct * 8;

  const int n = group * GK_NPB + w * 8 + g;
  const int e0 = ro[n], e1 = ro[n + 1];

  float acc[8] = {0.f, 0.f, 0.f, 0.f, 0.f, 0.f, 0.f, 0.f};
  float psum = 0.f;

  for (int eb = e0 & ~7; eb < e1; eb += 8) {
    const int4 sv0 = *(const int4*)(src + eb);
    const int4 sv1 = *(const int4*)(src + eb + 4);
    const float4 pv0 = *(const float4*)(ph + eb);
    const float4 pv1 = *(const float4*)(ph + eb + 4);
    int ss[8]; float pp[8];
    ss[0] = sv0.x; ss[1] = sv0.y; ss[2] = sv0.z; ss[3] = sv0.w;
    ss[4] = sv1.x; ss[5] = sv1.y; ss[6] = sv1.z; ss[7] = sv1.w;
    pp[0] = pv0.x; pp[1] = pv0.y; pp[2] = pv0.z; pp[3] = pv0.w;
    pp[4] = pv1.x; pp[5] = pv1.y; pp[6] = pv1.z; pp[7] = pv1.w;
#pragma unroll
    for (int j = 0; j < 8; j++) {
      const int e = eb + j;
      if (e < e0 || e >= e1) pp[j] = 0.f;
    }
    bf16x8 v[8];
#pragma unroll
    for (int j = 0; j < 8; j++)
      v[j] = *(const bf16x8*)(Hb + (size_t)ss[j] * 512 + dimbase);
#pragma unroll
    for (int j = 0; j < 8; j++) {
      psum += pp[j];
#pragma unroll
      for (int t = 0; t < 8; t++) acc[t] += pp[j] * (float)v[j][t];
    }
  }

  const float ih = psum > 0.f ? 1.0f / psum : 0.f;
  const float4 b0 = *(const float4*)(bias + dimbase);
  const float4 b1 = *(const float4*)(bias + dimbase + 4);
  bf16x8 o; float vv;
  vv = acc[0] * ih + b0.x; o[0] = (bf16_t)(vv > 0.f ? vv : expm1f(vv));
  vv = acc[1] * ih + b0.y; o[1] = (bf16_t)(vv > 0.f ? vv : expm1f(vv));
  vv = acc[2] * ih + b0.z; o[2] = (bf16_t)(vv > 0.f ? vv : expm1f(vv));
  vv = acc[3] * ih + b0.w; o[3] = (bf16_t)(vv > 0.f ? vv : expm1f(vv));
  vv = acc[4] * ih + b1.x; o[4] = (bf16_t)(vv > 0.f ? vv : expm1f(vv));
  vv = acc[5] * ih + b1.y; o[5] = (bf16_t)(vv > 0.f ? vv : expm1f(vv));
  vv = acc[6] * ih + b1.z; o[6] = (bf16_t)(vv > 0.f ? vv : expm1f(vv));
  vv = acc[7] * ih + b1.w; o[7] = (bf16_t)(vv > 0.f ? vv : expm1f(vv));
  *(bf16x8*)(out + (size_t)n * 512 + dimbase) = o;
}

// ------------- bf16 MFMA GEMM, BK=64, single-buffered 2-barrier -------------
// r23: per-regime tile split. GEMM1 (K=1280, latency-bound, NT=20): BM=64 ->
// 31% occupancy, measured 92.5->85 us (r22). GEMM2 (K=512, traffic-bound,
// NT=8): BM=128 -> minimal staged bytes, measured 26 us (r21); r22 showed
// BM=64 costs it ~+8 us via +50% B refetch. seg-XOR swizzle throughout.
// AF32=1: A fp32 (GEMM1, fused cast). EPI=0: bf16 C. EPI=1: fp32 elu(C+bias).
// EPI=2: bf16 C + fused el/er (BN=128==D; compile-time writer select).
template <int BM, int BN, int WM, int WN, int EPI, int AF32>
__global__ __launch_bounds__(256) void gemm_bt(
    const void* __restrict__ A, const bf16_t* __restrict__ Bt,
    void* __restrict__ C, const float* __restrict__ bias,
    const float* __restrict__ al, const float* __restrict__ ar,
    float* __restrict__ el, float* __restrict__ er,
    int M, int N, int K) {
  constexpr int BK = 64;
  constexpr int WTM = BM / WM, WTN = BN / WN;
  constexpr int MF = WTM / 16, NF = WTN / 16;
  using AT = typename std::conditional<AF32, float, bf16_t>::type;

  __shared__ AT sA[BM][BK];
  __shared__ bf16_t sB[BN][BK];
  __shared__ float s_red[2][BM][2];   // [el/er][row][wc] (EPI==2 only)

  const bf16_t* __restrict__ Ab = (const bf16_t*)A;
  const float* __restrict__ Af = (const float*)A;

  const int tid = threadIdx.x;
  const int wid = tid >> 6, lane = tid & 63;
  const int wr = wid / WN, wc = wid % WN;

  // XCD-chunked bijective swizzle (m204)
  const int nby = N / BN;
  const int nwg = gridDim.x;
  const int q = nwg >> 3, r = nwg & 7;
  const int xcd = blockIdx.x & 7, pos = blockIdx.x >> 3;
  const int wg = (xcd < r ? xcd * (q + 1) : r * (q + 1) + (xcd - r) * q) + pos;
  const int row0 = (wg / nby) * BM;
  const int col0 = (wg % nby) * BN;

  f32x4 acc[MF][NF];
#pragma unroll
  for (int i = 0; i < MF; i++)
#pragma unroll
    for (int j = 0; j < NF; j++) acc[i][j] = (f32x4){0.f, 0.f, 0.f, 0.f};

  // bf16 staging: 1 KB/issue = 8 rows of 128 B; lane -> row l>>3, phys seg l&7
  const int b_r = lane >> 3, b_p = lane & 7;
  // fp32 staging: 1 KB/issue = 4 rows of 256 B; lane -> row l>>4, phys seg l&15
  const int a_r = lane >> 4, a_p = lane & 15;

  for (int k0 = 0; k0 < K; k0 += BK) {
    if constexpr (AF32) {
#pragma unroll
      for (int j = 0; j < BM / 16; j++) {      // 4 rows per issue
        const int rj = (j * 4 + wid) * 4;
        const int row = rj + a_r;
        int grow = row0 + row; if (grow > M - 1) grow = M - 1;
        const int s = a_p ^ (row & 7);         // inverse swizzle on source
        gload_lds16(Af + (size_t)grow * K + k0 + s * 4, &sA[rj][0]);
      }
    } else {
#pragma unroll
      for (int j = 0; j < BM / 32; j++) {      // 8 rows per issue
        const int rj = (j * 4 + wid) * 8;
        const int row = rj + b_r;
        int grow = row0 + row; if (grow > M - 1) grow = M - 1;
        const int s = b_p ^ (row & 7);
        gload_lds16(Ab + (size_t)grow * K + k0 + s * 8, &sA[rj][0]);
      }
    }
#pragma unroll
    for (int j = 0; j < BN / 32; j++) {
      const int rj = (j * 4 + wid) * 8;
      const int row = rj + b_r;
      const int s = b_p ^ (row & 7);
      gload_lds16(Bt + (size_t)(col0 + row) * K + k0 + s * 8, &sB[rj][0]);
    }
    __syncthreads();

#pragma unroll
    for (int kk = 0; kk < BK; kk += 32) {
      bf16x8 af[MF], bfr[NF];
#pragma unroll
      for (int i = 0; i < MF; i++) {
        const int row = wr * WTM + i * 16 + (lane & 15);
        if constexpr (AF32) {
          const int s0 = kk / 4 + (lane >> 4) * 2;      // 16B segs of 4 floats
          const int p0 = s0 ^ (row & 7), p1 = (s0 + 1) ^ (row & 7);
          const f32x4 a0 = *(const f32x4*)&((const float*)&sA[row][0])[p0 * 4];
          const f32x4 a1 = *(const f32x4*)&((const float*)&sA[row][0])[p1 * 4];
#pragma unroll
          for (int t = 0; t < 4; t++) {
            af[i][t] = (bf16_t)a0[t];
            af[i][t + 4] = (bf16_t)a1[t];
          }
        } else {
          const int s = kk / 8 + (lane >> 4);           // 16B segs of 8 bf16
          const int p = s ^ (row & 7);
          af[i] = *(const bf16x8*)&((const bf16_t*)&sA[row][0])[p * 8];
        }
      }
#pragma unroll
      for (int j = 0; j < NF; j++) {
        const int row = wc * WTN + j * 16 + (lane & 15);
        const int s = kk / 8 + (lane >> 4);
        const int p = s ^ (row & 7);
        bfr[j] = *(const bf16x8*)&((const bf16_t*)&sB[row][0])[p * 8];
      }
#pragma unroll
      for (int i = 0; i < MF; i++)
#pragma unroll
        for (int j = 0; j < NF; j++)
          acc[i][j] = __builtin_amdgcn_mfma_f32_16x16x32_bf16(af[i], bfr[j], acc[i][j], 0, 0, 0);
    }
    __syncthreads();
  }

  // ---- C store ----
#pragma unroll
  for (int i = 0; i < MF; i++) {
#pragma unroll
    for (int j = 0; j < NF; j++) {
#pragma unroll
      for (int rr = 0; rr < 4; rr++) {
        int row = row0 + wr * WTM + i * 16 + (lane >> 4) * 4 + rr;
        int col = col0 + wc * WTN + j * 16 + (lane & 15);
        if (row < M) {
          float v = acc[i][j][rr];
          if constexpr (EPI == 1) {
            v += bias[col];
            v = v > 0.f ? v : expm1f(v);
            ((float*)C)[(size_t)row * N + col] = v;
          } else {
            ((bf16_t*)C)[(size_t)row * N + col] = (bf16_t)v;
          }
        }
      }
    }
  }

  // ---- fused el/er (EPI==2): this block's col range == head h ----
  if constexpr (EPI == 2) {
    const int h = col0 >> 7;  // BN==128==D
    float alv[NF], arv[NF];
#pragma unroll
    for (int j = 0; j < NF; j++) {
      const int d = wc * WTN + j * 16 + (lane & 15);   // col within head
      alv[j] = al[h * 128 + d];
      arv[j] = ar[h * 128 + d];
    }
    float tl[MF][4], tr[MF][4];
#pragma unroll
    for (int i = 0; i < MF; i++)
#pragma unroll
      for (int rr = 0; rr < 4; rr++) {
        float sl = 0.f, sr2 = 0.f;
#pragma unroll
        for (int j = 0; j < NF; j++) {
          sl  += acc[i][j][rr] * alv[j];
          sr2 += acc[i][j][rr] * arv[j];
        }
        tl[i][rr] = sl; tr[i][rr] = sr2;
      }
    // reduce across the 16-lane col-group (rows depend only on lane>>4)
#pragma unroll
    for (int msk = 1; msk < 16; msk <<= 1)
#pragma unroll
      for (int i = 0; i < MF; i++)
#pragma unroll
        for (int rr = 0; rr < 4; rr++) {
          tl[i][rr] += __shfl_xor(tl[i][rr], msk);
          tr[i][rr] += __shfl_xor(tr[i][rr], msk);
        }
    // writer select: compile-time indices only (rule #20)
    float outl = 0.f, outr = 0.f;
#pragma unroll
    for (int i = 0; i < MF; i++)
#pragma unroll
      for (int rr = 0; rr < 4; rr++)
        if ((lane & 15) == i * 4 + rr) { outl = tl[i][rr]; outr = tr[i][rr]; }
    {
      const int L = lane & 15;
      if (L < MF * 4) {
        const int rloc = wr * WTM + (L >> 2) * 16 + (lane >> 4) * 4 + (L & 3);
        s_red[0][rloc][wc] = outl;
        s_red[1][rloc][wc] = outr;
      }
    }
    __syncthreads();
    if (tid < BM) {
      const int row = row0 + tid;
      if (row < M) {
        el[(size_t)row * 4 + h] = s_red[0][tid][0] + s_red[0][tid][1];
        er[(size_t)row * 4 + h] = s_red[1][tid][0] + s_red[1][tid][1];
      }
    }
  }
}

extern "C" void kernel_launch(void* const* d_in, const int* in_sizes, int n_in,
                              void* d_out, int out_size, void* d_ws, size_t ws_size,
                              hipStream_t stream) {
  const float* feature = (const float*)d_in[0];
  const int* src = (const int*)d_in[1];
  const int* dst = (const int*)d_in[2];
  const float* W1 = (const float*)d_in[3];
  const float* al1 = (const float*)d_in[4];
  const float* ar1 = (const float*)d_in[5];
  const float* b1 = (const float*)d_in[6];
  const float* W2 = (const float*)d_in[7];
  const float* al2 = (const float*)d_in[8];
  const float* ar2 = (const float*)d_in[9];
  const float* b2 = (const float*)d_in[10];
  const float* Wfc = (const float*)d_in[11];
  const float* bfc = (const float*)d_in[12];

  const int N = 20000, E = 320000, INF = 1280, HD = 512;

  char* ws = (char*)d_ws;
  size_t off = 0;
  auto alloc = [&](size_t bytes) {
    void* p = ws + off;
    off += (bytes + 255) & ~(size_t)255;
    return p;
  };
  bf16_t* W1t = (bf16_t*)alloc((size_t)HD * INF * 2);
  bf16_t* W2t = (bf16_t*)alloc((size_t)HD * HD * 2);
  bf16_t* Wft = (bf16_t*)alloc((size_t)64 * HD * 2);
  bf16_t* Hb  = (bf16_t*)alloc((size_t)N * HD * 2);    // 20.5 MB
  bf16_t* Xn  = (bf16_t*)alloc((size_t)N * HD * 2);    // 20.5 MB
  float* el = (float*)alloc((size_t)N * 4 * 4);
  float* er = (float*)alloc((size_t)N * 4 * 4);
  float* pw = (float*)alloc((size_t)E * 4 * 4);        // 5.1 MB, planes [4][E]
  int* ro = (int*)alloc((size_t)(N + 1) * 4);

  // preprocessing
  {
    dim3 g(HD / 32, INF / 32);
    transk<<<g, 256, 0, stream>>>(W1, W1t, INF, HD);
  }
  {
    dim3 g(HD / 32, HD / 32);
    transk<<<g, 256, 0, stream>>>(W2, W2t, HD, HD);
  }
  {
    dim3 g(64 / 32, HD / 32);
    transk<<<g, 256, 0, stream>>>(Wfc, Wft, HD, 64);
  }
  rowoffk<<<(N + 1 + 255) / 256, 256, 0, stream>>>(dst, ro, N, E);

  const int nbx64 = (N + 63) / 64;        // 313
  const int nbx = (N + 127) / 128;        // 157
  const int gatherBlocks = (N / GK_NPB) * 8;   // 625 groups x 8 slices
  const int edgeBlocks = (E + 255) / 256;

  // layer 1: A = fp32 feature (cast fused), BM=64 (latency regime), fused el/er
  gemm_bt<64, 128, 2, 2, 2, 1><<<nbx64 * (HD / 128), 256, 0, stream>>>(
      feature, W1t, Hb, nullptr, al1, ar1, el, er, N, HD, INF);
  edgek<<<edgeBlocks, 256, 0, stream>>>(el, er, src, dst, pw, E);
  gatherk<<<gatherBlocks, 256, 0, stream>>>(Hb, pw, src, ro, b1, Xn, N, E);

  // layer 2: bf16 path, BM=128 (traffic regime), fused el/er
  gemm_bt<128, 128, 2, 2, 2, 0><<<nbx * (HD / 128), 256, 0, stream>>>(
      Xn, W2t, Hb, nullptr, al2, ar2, el, er, N, HD, HD);
  edgek<<<edgeBlocks, 256, 0, stream>>>(el, er, src, dst, pw, E);
  gatherk<<<gatherBlocks, 256, 0, stream>>>(Hb, pw, src, ro, b2, Xn, N, E);

  // final FC + elu -> d_out (fp32)
  gemm_bt<128, 64, 4, 1, 1, 0><<<nbx, 256, 0, stream>>>(
      Xn, Wft, d_out, bfc, nullptr, nullptr, nullptr, nullptr, N, 64, HD);
}